// Round 1
// baseline (270.648 us; speedup 1.0000x reference)
//
#include <hip/hip_runtime.h>

// Problem constants (from reference): T_MAX=32, F_DIM=128.
constexpr int TMAX = 32;
constexpr int FDIM = 128;

// One block (256 threads = 4 waves) per node.
//  Pass A: stage valid rows (t < len) of X[n] into LDS, float4-coalesced.
//  Pass B: per-timestep dot(X[n,t,:], wq) via 64-lane shuffle reduce (4 waves stride over t).
//  Pass C: out[n,f] = sum_t score[t] * X[n,t,f]; 128 features x 2 timestep-parity halves.
__global__ __launch_bounds__(256)
void aggregate_nodes_temporal_kernel(const float* __restrict__ x,      // (N, T, F)
                                     const int* __restrict__ lengths,  // (B,)
                                     const int* __restrict__ num_nodes,// (B,)
                                     const float* __restrict__ wq,     // (F,)
                                     float* __restrict__ out,          // (N, F)
                                     int N, int B) {
    __shared__ float sdata[TMAX * FDIM];  // 16 KB
    __shared__ float sscore[TMAX];
    __shared__ float swq[FDIM];
    __shared__ float spart[FDIM];

    const int n = blockIdx.x;
    if (n >= N) return;
    const int tid = threadIdx.x;

    // Map node -> graph via prefix over num_nodes (wave-uniform scalar loop, B=100).
    int g = 0;
    long long acc = 0;
    for (; g < B - 1; ++g) {
        long long c = num_nodes[g];
        if ((long long)n < acc + c) break;
        acc += c;
    }
    int len = lengths[g];
    if (len < 0) len = 0;
    if (len > TMAX) len = TMAX;

    if (tid < FDIM) swq[tid] = wq[tid];

    // Pass A: stage only the valid rows (this is the big win: ~half the HBM traffic).
    const float4* src = reinterpret_cast<const float4*>(x + (size_t)n * (TMAX * FDIM));
    float4* dst = reinterpret_cast<float4*>(sdata);
    const int nvec = len * (FDIM / 4);  // up to 1024 float4s
    for (int i = tid; i < nvec; i += 256) {
        dst[i] = src[i];
    }
    __syncthreads();

    // Pass B: scores[t] = dot(sdata[t][:], wq). Wave w handles t = w, w+4, ...
    const int wid = tid >> 6;
    const int lane = tid & 63;
    for (int t = wid; t < len; t += 4) {
        const float2 d = reinterpret_cast<const float2*>(sdata + t * FDIM)[lane];
        const float2 q = reinterpret_cast<const float2*>(swq)[lane];
        float p = d.x * q.x + d.y * q.y;
#pragma unroll
        for (int off = 32; off >= 1; off >>= 1)
            p += __shfl_xor(p, off, 64);
        if (lane == 0) sscore[t] = p;
    }
    __syncthreads();

    // Pass C: weighted temporal sum. tid<128 handles even t, tid>=128 odd t, same feature f.
    const int f = tid & (FDIM - 1);
    const int parity = tid >> 7;  // 0 or 1
    float a = 0.0f;
    for (int t = parity; t < len; t += 2)
        a += sscore[t] * sdata[t * FDIM + f];

    if (parity == 1) spart[f] = a;  // always written (0 if no iterations)
    __syncthreads();
    if (parity == 0)
        out[(size_t)n * FDIM + f] = a + spart[f];
}

extern "C" void kernel_launch(void* const* d_in, const int* in_sizes, int n_in,
                              void* d_out, int out_size, void* d_ws, size_t ws_size,
                              hipStream_t stream) {
    const float* x = (const float*)d_in[0];        // nodes_output (N,T,F) fp32
    const int* lengths = (const int*)d_in[1];      // (B,)
    const int* num_nodes = (const int*)d_in[2];    // (B,)
    const float* wq = (const float*)d_in[3];       // (F,)
    float* out = (float*)d_out;                    // (N,F) fp32

    const int N = in_sizes[0] / (TMAX * FDIM);
    const int B = in_sizes[1];

    aggregate_nodes_temporal_kernel<<<N, 256, 0, stream>>>(x, lengths, num_nodes, wq, out, N, B);
}

// Round 2
// 143.690 us; speedup vs baseline: 1.8836x; 1.8836x over previous
//
#include <hip/hip_runtime.h>

// Problem constants (from reference): T_MAX=32, F_DIM=128.
constexpr int TMAX = 32;
constexpr int FDIM = 128;

// Kernel 0: exclusive prefix sum of num_nodes into ws[0..B] (single block).
// B is small (~100); serial scan by thread 0 is fine and runs once.
__global__ void prefix_kernel(const int* __restrict__ num_nodes, int* __restrict__ prefix, int B) {
    if (threadIdx.x == 0 && blockIdx.x == 0) {
        int acc = 0;
        for (int g = 0; g < B; ++g) {
            prefix[g] = acc;
            acc += num_nodes[g];
        }
        prefix[B] = acc;
    }
}

// One block (256 threads = 4 waves) per node.
//  Lookup: g via parallel range-check against precomputed prefix (O(1) latency).
//  Pass A: stage valid rows (t < len) of X[n] into LDS, float4-coalesced.
//  Pass B: per-timestep dot(X[n,t,:], wq) via 64-lane shuffle reduce.
//  Pass C: out[n,f] = sum_t score[t] * X[n,t,f]; feature x timestep-parity split.
__global__ __launch_bounds__(256)
void aggregate_nodes_temporal_kernel(const float* __restrict__ x,      // (N, T, F)
                                     const int* __restrict__ lengths,  // (B,)
                                     const int* __restrict__ prefix,   // (B+1,) in ws
                                     const float* __restrict__ wq,     // (F,)
                                     float* __restrict__ out,          // (N, F)
                                     int N, int B) {
    __shared__ float sdata[TMAX * FDIM];  // 16 KB
    __shared__ float sscore[TMAX];
    __shared__ float swq[FDIM];
    __shared__ float spart[FDIM];
    __shared__ int s_g;

    const int n = blockIdx.x;
    if (n >= N) return;
    const int tid = threadIdx.x;

    // O(1)-latency graph lookup: each lane checks one range (all loads L1/L2-cached).
    for (int i = tid; i < B; i += 256) {
        if (prefix[i] <= n && n < prefix[i + 1]) s_g = i;
    }
    if (tid < FDIM) swq[tid] = wq[tid];
    __syncthreads();

    const int g = s_g;
    int len = lengths[g];
    if (len < 0) len = 0;
    if (len > TMAX) len = TMAX;

    // Pass A: stage only the valid rows (reads ~len/TMAX of the input).
    const float4* src = reinterpret_cast<const float4*>(x + (size_t)n * (TMAX * FDIM));
    float4* dst = reinterpret_cast<float4*>(sdata);
    const int nvec = len * (FDIM / 4);  // up to 1024 float4s
    for (int i = tid; i < nvec; i += 256) {
        dst[i] = src[i];
    }
    __syncthreads();

    // Pass B: scores[t] = dot(sdata[t][:], wq). Wave w handles t = w, w+4, ...
    const int wid = tid >> 6;
    const int lane = tid & 63;
    for (int t = wid; t < len; t += 4) {
        const float2 d = reinterpret_cast<const float2*>(sdata + t * FDIM)[lane];
        const float2 q = reinterpret_cast<const float2*>(swq)[lane];
        float p = d.x * q.x + d.y * q.y;
#pragma unroll
        for (int off = 32; off >= 1; off >>= 1)
            p += __shfl_xor(p, off, 64);
        if (lane == 0) sscore[t] = p;
    }
    __syncthreads();

    // Pass C: weighted temporal sum. tid<128 -> even t, tid>=128 -> odd t, same feature f.
    const int f = tid & (FDIM - 1);
    const int parity = tid >> 7;  // 0 or 1
    float a = 0.0f;
    for (int t = parity; t < len; t += 2)
        a += sscore[t] * sdata[t * FDIM + f];

    if (parity == 1) spart[f] = a;  // always written (0 if no iterations)
    __syncthreads();
    if (parity == 0)
        out[(size_t)n * FDIM + f] = a + spart[f];
}

extern "C" void kernel_launch(void* const* d_in, const int* in_sizes, int n_in,
                              void* d_out, int out_size, void* d_ws, size_t ws_size,
                              hipStream_t stream) {
    const float* x = (const float*)d_in[0];        // nodes_output (N,T,F) fp32
    const int* lengths = (const int*)d_in[1];      // (B,)
    const int* num_nodes = (const int*)d_in[2];    // (B,)
    const float* wq = (const float*)d_in[3];       // (F,)
    float* out = (float*)d_out;                    // (N,F) fp32

    const int N = in_sizes[0] / (TMAX * FDIM);
    const int B = in_sizes[1];

    int* prefix = (int*)d_ws;  // B+1 ints

    prefix_kernel<<<1, 64, 0, stream>>>(num_nodes, prefix, B);
    aggregate_nodes_temporal_kernel<<<N, 256, 0, stream>>>(x, lengths, prefix, wq, out, N, B);
}

// Round 3
// 103.720 us; speedup vs baseline: 2.6094x; 1.3854x over previous
//
#include <hip/hip_runtime.h>

// Problem constants (from reference): T_MAX=32, F_DIM=128.
constexpr int TMAX = 32;
constexpr int FDIM = 128;

// Kernel 0: exclusive prefix sum of num_nodes into ws[0..B] (single block, B~100).
__global__ void prefix_kernel(const int* __restrict__ num_nodes, int* __restrict__ prefix, int B) {
    if (threadIdx.x == 0 && blockIdx.x == 0) {
        int acc = 0;
        for (int g = 0; g < B; ++g) {
            prefix[g] = acc;
            acc += num_nodes[g];
        }
        prefix[B] = acc;
    }
}

// Wave-per-node, fully register-resident, no LDS, no __syncthreads.
//  - lane l owns features (2l, 2l+1) as float2; row[t] kept in VGPRs (unrolled, static idx).
//  - all valid-row loads issue up front (deep vmcnt pipeline, coalesced 512B/wave/row);
//    rows with t >= len are skipped entirely (uniform branch) -> ~len/32 of input fetched.
//  - per t: partial dot (2 FMA) -> 64-lane xor-butterfly reduce (score broadcast to all
//    lanes for free) -> acc += score * row[t] (2 FMA). Store float2 per lane, coalesced.
__global__ __launch_bounds__(256)
void aggregate_nodes_temporal_kernel(const float* __restrict__ x,      // (N, T, F)
                                     const int* __restrict__ lengths,  // (B,)
                                     const int* __restrict__ prefix,   // (B+1,) in ws
                                     const float* __restrict__ wq,     // (F,)
                                     float* __restrict__ out,          // (N, F)
                                     int N, int B) {
    const int lane = threadIdx.x & 63;
    const int wid = threadIdx.x >> 6;
    const int n = blockIdx.x * 4 + wid;
    if (n >= N) return;  // wave-uniform exit

    // Graph lookup: g = (# prefix entries <= n) - 1, via ballots (2 iters for B~100).
    int cnt = 0;
    for (int base = 0; base <= B; base += 64) {
        const int i = base + lane;
        const bool ok = (i <= B) && (prefix[i] <= n);
        cnt += __popcll(__ballot(ok));
    }
    const int g = cnt - 1;
    int len = lengths[g];
    if (len < 0) len = 0;
    if (len > TMAX) len = TMAX;

    const float2 wqv = reinterpret_cast<const float2*>(wq)[lane];
    const float2* src = reinterpret_cast<const float2*>(x) + (size_t)n * (TMAX * (FDIM / 2)) + lane;

    // Phase 1: issue all valid-row loads into registers (static indices after unroll).
    float2 row[TMAX];
#pragma unroll
    for (int t = 0; t < TMAX; ++t) {
        if (t < len) row[t] = src[t * (FDIM / 2)];
    }

    // Phase 2: score[t] = dot(row_t, wq) reduced across the wave; fuse weighted sum.
    float2 acc = make_float2(0.0f, 0.0f);
#pragma unroll
    for (int t = 0; t < TMAX; ++t) {
        if (t < len) {
            float p = row[t].x * wqv.x + row[t].y * wqv.y;
#pragma unroll
            for (int off = 32; off >= 1; off >>= 1)
                p += __shfl_xor(p, off, 64);
            acc.x += p * row[t].x;
            acc.y += p * row[t].y;
        }
    }

    reinterpret_cast<float2*>(out)[(size_t)n * (FDIM / 2) + lane] = acc;
}

extern "C" void kernel_launch(void* const* d_in, const int* in_sizes, int n_in,
                              void* d_out, int out_size, void* d_ws, size_t ws_size,
                              hipStream_t stream) {
    const float* x = (const float*)d_in[0];        // nodes_output (N,T,F) fp32
    const int* lengths = (const int*)d_in[1];      // (B,)
    const int* num_nodes = (const int*)d_in[2];    // (B,)
    const float* wq = (const float*)d_in[3];       // (F,)
    float* out = (float*)d_out;                    // (N,F) fp32

    const int N = in_sizes[0] / (TMAX * FDIM);
    const int B = in_sizes[1];

    int* prefix = (int*)d_ws;  // B+1 ints

    prefix_kernel<<<1, 64, 0, stream>>>(num_nodes, prefix, B);
    const int blocks = (N + 3) / 4;  // 4 waves/block, one node per wave
    aggregate_nodes_temporal_kernel<<<blocks, 256, 0, stream>>>(x, lengths, prefix, wq, out, N, B);
}

// Round 4
// 88.541 us; speedup vs baseline: 3.0567x; 1.1714x over previous
//
#include <hip/hip_runtime.h>

// Problem constants (from reference): T_MAX=32, F_DIM=128.
constexpr int TMAX = 32;
constexpr int FDIM = 128;

// Wave-per-node, register-resident, no LDS, no __syncthreads, no helper kernel.
//  - Graph lookup: per-wave inclusive scan (shfl_up) of num_nodes + ballot count.
//  - Layout: lanes 0-31 own row 2k (features 4f..4f+3 as float4), lanes 32-63 own
//    row 2k+1. One global_load_dwordx4 fetches TWO rows (1024 B/wave).
//  - Rows with t >= len: zero-filled, load exec-masked off per lane -> no fetch.
//  - Per pair k: p = dot4(row, wq4); 5-step xor-butterfly within each 32-lane half
//    yields that half's row score broadcast; acc += p * row. Scores of zeroed rows
//    are exactly 0, so they contribute nothing.
//  - Epilogue: cross-half combine via shfl_xor(...,32); lanes 0-31 store float4.
__global__ __launch_bounds__(256)
void aggregate_nodes_temporal_kernel(const float* __restrict__ x,      // (N, T, F)
                                     const int* __restrict__ lengths,  // (B,)
                                     const int* __restrict__ num_nodes,// (B,)
                                     const float* __restrict__ wq,     // (F,)
                                     float* __restrict__ out,          // (N, F)
                                     int N, int B) {
    const int lane = threadIdx.x & 63;
    const int wid = threadIdx.x >> 6;
    const int n = blockIdx.x * 4 + wid;
    if (n >= N) return;  // wave-uniform exit

    // Graph lookup: g = #{i : inclusive_prefix(num_nodes)[i] <= n}.
    int cnt = 0;
    int carry = 0;
    for (int base = 0; base < B; base += 64) {
        int v = (base + lane < B) ? num_nodes[base + lane] : 0;
#pragma unroll
        for (int off = 1; off < 64; off <<= 1) {
            int u = __shfl_up(v, off, 64);
            v += (lane >= off) ? u : 0;
        }
        const int incl = v + carry;
        cnt += __popcll(__ballot(incl <= n));
        carry = __shfl(incl, 63, 64);
    }
    const int g = cnt;

    int len = lengths[g];
    if (len < 0) len = 0;
    if (len > TMAX) len = TMAX;

    const int half = lane >> 5;   // 0: even rows, 1: odd rows
    const int fl = lane & 31;     // float4 slot within a row (feature 4*fl..4*fl+3)
    const float4 wq4 = reinterpret_cast<const float4*>(wq)[fl];
    const float4* src = reinterpret_cast<const float4*>(x)
                      + (size_t)n * (TMAX * (FDIM / 4)) + half * (FDIM / 4) + fl;

    // Phase 1: issue all valid loads back-to-back (static indices after unroll).
    float4 row[TMAX / 2];
#pragma unroll
    for (int k = 0; k < TMAX / 2; ++k) {
        row[k] = make_float4(0.0f, 0.0f, 0.0f, 0.0f);
        if (2 * k + half < len)            // per-lane exec mask at the odd tail
            row[k] = src[k * (2 * FDIM / 4)];
    }

    // Phase 2: per-pair score reduce + fused weighted accumulation.
    float4 acc = make_float4(0.0f, 0.0f, 0.0f, 0.0f);
#pragma unroll
    for (int k = 0; k < TMAX / 2; ++k) {
        if (2 * k < len) {                 // wave-uniform: pair has >=1 valid row
            float p = row[k].x * wq4.x + row[k].y * wq4.y
                    + row[k].z * wq4.z + row[k].w * wq4.w;
#pragma unroll
            for (int off = 1; off < 32; off <<= 1)
                p += __shfl_xor(p, off, 64);  // reduce within each 32-lane half
            acc.x += p * row[k].x;
            acc.y += p * row[k].y;
            acc.z += p * row[k].z;
            acc.w += p * row[k].w;
        }
    }

    // Epilogue: combine even/odd halves, store from lanes 0-31 (coalesced 512 B).
    acc.x += __shfl_xor(acc.x, 32, 64);
    acc.y += __shfl_xor(acc.y, 32, 64);
    acc.z += __shfl_xor(acc.z, 32, 64);
    acc.w += __shfl_xor(acc.w, 32, 64);
    if (half == 0)
        reinterpret_cast<float4*>(out)[(size_t)n * (FDIM / 4) + fl] = acc;
}

extern "C" void kernel_launch(void* const* d_in, const int* in_sizes, int n_in,
                              void* d_out, int out_size, void* d_ws, size_t ws_size,
                              hipStream_t stream) {
    const float* x = (const float*)d_in[0];        // nodes_output (N,T,F) fp32
    const int* lengths = (const int*)d_in[1];      // (B,)
    const int* num_nodes = (const int*)d_in[2];    // (B,)
    const float* wq = (const float*)d_in[3];       // (F,)
    float* out = (float*)d_out;                    // (N,F) fp32

    const int N = in_sizes[0] / (TMAX * FDIM);
    const int B = in_sizes[1];

    const int blocks = (N + 3) / 4;  // 4 waves/block, one node per wave
    aggregate_nodes_temporal_kernel<<<blocks, 256, 0, stream>>>(x, lengths, num_nodes, wq, out, N, B);
}

// Round 6
// 85.874 us; speedup vs baseline: 3.1517x; 1.0311x over previous
//
#include <hip/hip_runtime.h>

// Problem constants (from reference): T_MAX=32, F_DIM=128.
constexpr int TMAX = 32;
constexpr int FDIM = 128;

// DPP xor-add: x += lane_xor_k(x) using VALU DPP instead of DS. ctrl must be an
// immediate -> template parameter.
//  0xB1  = quad_perm(1,0,3,2)  -> xor1
//  0x4E  = quad_perm(2,3,0,1)  -> xor2
//  0x141 = row_half_mirror (i^7 within 8)  -> acts as xor4 on 4-group sums
//  0x140 = row_mirror      (i^15 within 16)-> acts as xor8 on 8-group sums
template <int CTRL>
__device__ __forceinline__ float dpp_xor_add(float x) {
    int y = __builtin_amdgcn_update_dpp(0, __float_as_int(x), CTRL, 0xF, 0xF, true);
    return x + __int_as_float(y);
}

// Wave-per-node, register-resident, no LDS tiles, no __syncthreads.
//  - Graph lookup: per-wave inclusive scan (shfl_up) of num_nodes + ballot count.
//  - Layout: lanes 0-31 own row 2k, lanes 32-63 own row 2k+1 (float4/lane).
//  - Rows with t >= len: zero-filled, load exec-masked -> ~len/32 of input fetched.
//  - Per pair: dot4 -> 4 DPP xor-adds (VALU) + 1 ds_swizzle(xor16) gives the row
//    score broadcast across its 32-lane half; acc += score * row.
//  - Epilogue: cross-half combine via shfl_xor(...,32); lanes 0-31 store float4.
__global__ __launch_bounds__(256)
void aggregate_nodes_temporal_kernel(const float* __restrict__ x,      // (N, T, F)
                                     const int* __restrict__ lengths,  // (B,)
                                     const int* __restrict__ num_nodes,// (B,)
                                     const float* __restrict__ wq,     // (F,)
                                     float* __restrict__ out,          // (N, F)
                                     int N, int B) {
    const int lane = threadIdx.x & 63;
    const int wid = threadIdx.x >> 6;
    const int n = blockIdx.x * 4 + wid;
    if (n >= N) return;  // wave-uniform exit

    // Graph lookup: g = #{i : inclusive_prefix(num_nodes)[i] <= n}.
    int cnt = 0;
    int carry = 0;
    for (int base = 0; base < B; base += 64) {
        int v = (base + lane < B) ? num_nodes[base + lane] : 0;
#pragma unroll
        for (int off = 1; off < 64; off <<= 1) {
            int u = __shfl_up(v, off, 64);
            v += (lane >= off) ? u : 0;
        }
        const int incl = v + carry;
        cnt += __popcll(__ballot(incl <= n));
        carry = __shfl(incl, 63, 64);
    }
    const int g = cnt;

    int len = lengths[g];
    if (len < 0) len = 0;
    if (len > TMAX) len = TMAX;

    const int half = lane >> 5;   // 0: even rows, 1: odd rows
    const int fl = lane & 31;     // float4 slot within a row (feature 4*fl..4*fl+3)
    const float4 wq4 = reinterpret_cast<const float4*>(wq)[fl];
    const float4* src = reinterpret_cast<const float4*>(x)
                      + (size_t)n * (TMAX * (FDIM / 4)) + half * (FDIM / 4) + fl;

    // Phase 1: issue all valid loads back-to-back (static indices after unroll).
    float4 row[TMAX / 2];
#pragma unroll
    for (int k = 0; k < TMAX / 2; ++k) {
        row[k] = make_float4(0.0f, 0.0f, 0.0f, 0.0f);
        if (2 * k + half < len)            // per-lane exec mask at the odd tail
            row[k] = src[k * (2 * FDIM / 4)];
    }

    // Phase 2: per-pair score reduce (DPP butterfly + one xor16 swizzle) + fused
    // weighted accumulation. Zeroed rows produce score 0 -> no contribution.
    float4 acc = make_float4(0.0f, 0.0f, 0.0f, 0.0f);
#pragma unroll
    for (int k = 0; k < TMAX / 2; ++k) {
        if (2 * k < len) {                 // wave-uniform: pair has >=1 valid row
            float p = row[k].x * wq4.x + row[k].y * wq4.y
                    + row[k].z * wq4.z + row[k].w * wq4.w;
            p = dpp_xor_add<0xB1>(p);      // xor1  (VALU)
            p = dpp_xor_add<0x4E>(p);      // xor2  (VALU)
            p = dpp_xor_add<0x141>(p);     // xor4-equiv (VALU)
            p = dpp_xor_add<0x140>(p);     // xor8-equiv (VALU)
            // xor16 within each 32-lane group: ds_swizzle BitMode 0x401F.
            int ps = __builtin_amdgcn_ds_swizzle(__float_as_int(p), 0x401F);
            p += __int_as_float(ps);
            acc.x += p * row[k].x;
            acc.y += p * row[k].y;
            acc.z += p * row[k].z;
            acc.w += p * row[k].w;
        }
    }

    // Epilogue: combine even/odd halves, store from lanes 0-31 (coalesced 512 B).
    acc.x += __shfl_xor(acc.x, 32, 64);
    acc.y += __shfl_xor(acc.y, 32, 64);
    acc.z += __shfl_xor(acc.z, 32, 64);
    acc.w += __shfl_xor(acc.w, 32, 64);
    if (half == 0)
        reinterpret_cast<float4*>(out)[(size_t)n * (FDIM / 4) + fl] = acc;
}

extern "C" void kernel_launch(void* const* d_in, const int* in_sizes, int n_in,
                              void* d_out, int out_size, void* d_ws, size_t ws_size,
                              hipStream_t stream) {
    const float* x = (const float*)d_in[0];        // nodes_output (N,T,F) fp32
    const int* lengths = (const int*)d_in[1];      // (B,)
    const int* num_nodes = (const int*)d_in[2];    // (B,)
    const float* wq = (const float*)d_in[3];       // (F,)
    float* out = (float*)d_out;                    // (N,F) fp32

    const int N = in_sizes[0] / (TMAX * FDIM);
    const int B = in_sizes[1];

    const int blocks = (N + 3) / 4;  // 4 waves/block, one node per wave
    aggregate_nodes_temporal_kernel<<<blocks, 256, 0, stream>>>(x, lengths, num_nodes, wq, out, N, B);
}